// Round 4
// baseline (3816.107 us; speedup 1.0000x reference)
//
#include <hip/hip_runtime.h>
#include <math.h>

#define H_COEF 0.1f
#define LN_EPS 1e-5

// LDS tile: 64 channels x 256 edges, XOR-swizzled so that
//  - per-thread column access (fixed t, c=0..63) is bank-conflict-free
//  - cooperative linear copies are <=4-way conflicted
// idx(c, el) = c*256 + (el ^ c), c in [0,64), el in [0,256).
__device__ __forceinline__ int lds_idx(int c, int el) {
  return (c << 8) + (el ^ c);
}

// ---------------------------------------------------------------------------
// Block-level (sum, sumsq) reduction -> atomicAdd(double) to global stat[2].
// ---------------------------------------------------------------------------
__device__ __forceinline__ void stat_reduce(float s, float ss, double* stat) {
#pragma unroll
  for (int off = 32; off > 0; off >>= 1) {
    s += __shfl_down(s, off);
    ss += __shfl_down(ss, off);
  }
  __shared__ float bs[8], bss[8];
  const int wid = threadIdx.x >> 6;
  const int lane = threadIdx.x & 63;
  if (lane == 0) { bs[wid] = s; bss[wid] = ss; }
  __syncthreads();
  if (threadIdx.x == 0) {
    float S = 0.f, SS = 0.f;
    const int nw = blockDim.x >> 6;
    for (int w = 0; w < nw; w++) { S += bs[w]; SS += bss[w]; }
    atomicAdd(stat, (double)S);
    atomicAdd(stat + 1, (double)SS);
  }
}

// ---------------------------------------------------------------------------
// CSR construction (per launch; indices are fixed inputs).
// ---------------------------------------------------------------------------
__global__ __launch_bounds__(256) void hist_kernel(
    const int* __restrict__ iInd, const int* __restrict__ jInd,
    int* __restrict__ cnt_i, int* __restrict__ cnt_j, int E) {
  const int e = blockIdx.x * blockDim.x + threadIdx.x;
  if (e < E) {
    atomicAdd(&cnt_i[iInd[e]], 1);
    atomicAdd(&cnt_j[jInd[e]], 1);
  }
}

__global__ __launch_bounds__(1024) void scan_kernel(
    const int* __restrict__ cnt_i, const int* __restrict__ cnt_j,
    int* __restrict__ rowptr_i, int* __restrict__ cursor_i,
    int* __restrict__ rowptr_j, int* __restrict__ cursor_j, int N) {
  __shared__ int carry;
  __shared__ int tmp[1024];
  for (int pass = 0; pass < 2; ++pass) {
    const int* cnt = pass ? cnt_j : cnt_i;
    int* rp = pass ? rowptr_j : rowptr_i;
    int* cur = pass ? cursor_j : cursor_i;
    if (threadIdx.x == 0) carry = 0;
    __syncthreads();
    for (int base = 0; base < N; base += 1024) {
      const int idx = base + threadIdx.x;
      const int v = (idx < N) ? cnt[idx] : 0;
      tmp[threadIdx.x] = v;
      int acc = v;
      __syncthreads();
      for (int off = 1; off < 1024; off <<= 1) {
        const int add = (threadIdx.x >= off) ? tmp[threadIdx.x - off] : 0;
        __syncthreads();
        acc += add;
        tmp[threadIdx.x] = acc;
        __syncthreads();
      }
      const int excl = acc - v + carry;
      if (idx < N) { rp[idx] = excl; cur[idx] = excl; }
      __syncthreads();
      if (threadIdx.x == 1023) carry += tmp[1023];
      __syncthreads();
    }
    if (threadIdx.x == 0) rp[N] = carry;
    __syncthreads();
  }
}

__global__ __launch_bounds__(256) void fill_kernel(
    const int* __restrict__ iInd, const int* __restrict__ jInd,
    int* __restrict__ cursor_i, int* __restrict__ cursor_j,
    int* __restrict__ perm_i, int* __restrict__ perm_j, int E) {
  const int e = blockIdx.x * blockDim.x + threadIdx.x;
  if (e < E) {
    perm_i[atomicAdd(&cursor_i[iInd[e]], 1)] = e;
    perm_j[atomicAdd(&cursor_j[jInd[e]], 1)] = e;
  }
}

// ---------------------------------------------------------------------------
// out(64 x M) = W(64 x KIN) @ xin(KIN x M).  One thread per column.
// ---------------------------------------------------------------------------
template <int KIN>
__global__ __launch_bounds__(256) void open_kernel(
    const float* __restrict__ W, const float* __restrict__ xin,
    float* __restrict__ out, int M) {
  const int e = blockIdx.x * blockDim.x + threadIdx.x;
  if (e >= M) return;
  float x[KIN];
#pragma unroll
  for (int k = 0; k < KIN; k++) x[k] = xin[(size_t)k * M + e];
#pragma unroll
  for (int c = 0; c < 64; c++) {
    float acc = 0.f;
#pragma unroll
    for (int k = 0; k < KIN; k++) acc += W[c * KIN + k] * x[k];
    out[(size_t)c * M + e] = acc;
  }
}

__global__ __launch_bounds__(256) void close_inplace_kernel(
    const float* __restrict__ W, float* x, int M) {
  const int e = blockIdx.x * blockDim.x + threadIdx.x;
  if (e >= M) return;
  float xv[64];
#pragma unroll
  for (int k = 0; k < 64; k++) xv[k] = x[(size_t)k * M + e];
#pragma unroll
  for (int c = 0; c < 64; c++) {
    float acc = 0.f;
#pragma unroll
    for (int k = 0; k < 64; k++) acc += W[c * 64 + k] * xv[k];
    x[(size_t)c * M + e] = acc;
  }
}

// ---------------------------------------------------------------------------
// U[n][c] = sum_k (0.5*KE1[c][k] + KE1[c][128+k]) * xn[k][n]
// V[n][c] = sum_k (0.5*KE1[c][k] - KE1[c][128+k]) * xn[k][n]
// ---------------------------------------------------------------------------
__global__ __launch_bounds__(256) void uv_kernel(
    const float* __restrict__ KE1_l, const float* __restrict__ xn,
    float* __restrict__ U, float* __restrict__ V, int N) {
  const int n = blockIdx.x * blockDim.x + threadIdx.x;
  if (n >= N) return;
  float x[64];
#pragma unroll
  for (int k = 0; k < 64; k++) x[k] = xn[(size_t)k * N + n];
#pragma unroll
  for (int c = 0; c < 64; c++) {
    const float* row = KE1_l + c * 192;
    float a = 0.f, g = 0.f;
#pragma unroll
    for (int k = 0; k < 64; k++) {
      a += row[k] * x[k];
      g += row[128 + k] * x[k];
    }
    U[(size_t)n * 64 + c] = 0.5f * a + g;
    V[(size_t)n * 64 + c] = 0.5f * a - g;
  }
}

// ---------------------------------------------------------------------------
// edge1: y[e][:] = U[i(e)][:] + V[j(e)][:] + B1 @ xe[:,e];  stats of y.
// y row-major [E][64]; rows staged via LDS so global stores are full-line.
// ---------------------------------------------------------------------------
__global__ __launch_bounds__(256) void edge1_kernel(
    const float* __restrict__ KE1_l, const float* __restrict__ xe,
    const float* __restrict__ U, const float* __restrict__ V,
    const int* __restrict__ iInd, const int* __restrict__ jInd,
    float* __restrict__ y, double* __restrict__ stat, int E) {
  __shared__ float sbuf[16384];
  const int t = threadIdx.x;
  const int base = blockIdx.x * 256;
  const int e = base + t;
  const bool full = (base + 256 <= E);
  float s = 0.f, ss = 0.f;
  if (e < E) {
    const int vi = iInd[e];
    const int vj = jInd[e];
    const float4* Up = (const float4*)(U + (size_t)vi * 64);
    const float4* Vp = (const float4*)(V + (size_t)vj * 64);
    float x[64];
#pragma unroll
    for (int k = 0; k < 64; k++) x[k] = xe[(size_t)k * E + e];
#pragma unroll
    for (int q = 0; q < 16; q++) {
      float4 uq = Up[q];
      float4 vq = Vp[q];
      const float* up = (const float*)&uq;
      const float* vp = (const float*)&vq;
#pragma unroll
      for (int u = 0; u < 4; u++) {
        const int c = q * 4 + u;
        const float* row = KE1_l + c * 192 + 64;
        float acc = up[u] + vp[u];
#pragma unroll
        for (int k = 0; k < 64; k++) acc += row[k] * x[k];
        s += acc;
        ss += acc * acc;
        if (full) sbuf[lds_idx(c, t)] = acc;
        else y[(size_t)e * 64 + c] = acc;
      }
    }
  }
  if (full) {
    __syncthreads();
    float4* dst = (float4*)(y + (size_t)base * 64);
#pragma unroll
    for (int it = 0; it < 16; it++) {
      const int f4 = t + it * 256;
      const int el = f4 >> 4;
      const int cb = (f4 & 15) << 2;
      float4 r;
      r.x = sbuf[lds_idx(cb + 0, el)];
      r.y = sbuf[lds_idx(cb + 1, el)];
      r.z = sbuf[lds_idx(cb + 2, el)];
      r.w = sbuf[lds_idx(cb + 3, el)];
      dst[f4] = r;
    }
  }
  stat_reduce(s, ss, stat);
}

// ---------------------------------------------------------------------------
// edge2: t = relu(ln(y row)); y row <- KE2 @ t (in place); stats of new y.
// Both directions staged via LDS.
// ---------------------------------------------------------------------------
__global__ __launch_bounds__(256) void edge2_kernel(
    const float* __restrict__ W, float* y, const double* __restrict__ statIn,
    double* __restrict__ statOut, double inv_n, int E) {
  __shared__ float sbuf[16384];
  const int t = threadIdx.x;
  const int base = blockIdx.x * 256;
  const int e = base + t;
  const bool full = (base + 256 <= E);
  float s = 0.f, ss = 0.f;
  if (full) {
    const float4* src = (const float4*)(y + (size_t)base * 64);
#pragma unroll
    for (int it = 0; it < 16; it++) {
      const int f4 = t + it * 256;
      const int el = f4 >> 4;
      const int cb = (f4 & 15) << 2;
      float4 r = src[f4];
      sbuf[lds_idx(cb + 0, el)] = r.x;
      sbuf[lds_idx(cb + 1, el)] = r.y;
      sbuf[lds_idx(cb + 2, el)] = r.z;
      sbuf[lds_idx(cb + 3, el)] = r.w;
    }
    __syncthreads();
  }
  if (e < E) {
    const double m = statIn[0] * inv_n;
    const double v = statIn[1] * inv_n - m * m;
    const float fm = (float)m;
    const float finv = (float)(1.0 / sqrt(v + LN_EPS));
    float tv[64];
    if (full) {
#pragma unroll
      for (int c = 0; c < 64; c++) {
        const float val = (sbuf[lds_idx(c, t)] - fm) * finv;
        tv[c] = val > 0.f ? val : 0.f;
      }
    } else {
#pragma unroll
      for (int c = 0; c < 64; c++) {
        const float val = (y[(size_t)e * 64 + c] - fm) * finv;
        tv[c] = val > 0.f ? val : 0.f;
      }
    }
    // thread t owns LDS column t exclusively: safe read-then-overwrite.
#pragma unroll
    for (int c = 0; c < 64; c++) {
      float acc = 0.f;
#pragma unroll
      for (int k = 0; k < 64; k++) acc += W[c * 64 + k] * tv[k];
      s += acc;
      ss += acc * acc;
      if (full) sbuf[lds_idx(c, t)] = acc;
      else y[(size_t)e * 64 + c] = acc;
    }
  }
  if (full) {
    __syncthreads();
    float4* dst = (float4*)(y + (size_t)base * 64);
#pragma unroll
    for (int it = 0; it < 16; it++) {
      const int f4 = t + it * 256;
      const int el = f4 >> 4;
      const int cb = (f4 & 15) << 2;
      float4 r;
      r.x = sbuf[lds_idx(cb + 0, el)];
      r.y = sbuf[lds_idx(cb + 1, el)];
      r.z = sbuf[lds_idx(cb + 2, el)];
      r.w = sbuf[lds_idx(cb + 3, el)];
      dst[f4] = r;
    }
  }
  stat_reduce(s, ss, statOut);
}

// ---------------------------------------------------------------------------
// edge3: t2 = relu(ln(y row));  xe col += H * (KE3 @ t2);
//        y row <- t2  (so the gather is a plain row-sum).
// ---------------------------------------------------------------------------
__global__ __launch_bounds__(256) void edge3_kernel(
    const float* __restrict__ W, float* __restrict__ y, float* xe,
    const double* __restrict__ statIn, double inv_n, int E) {
  __shared__ float sbuf[16384];
  const int t = threadIdx.x;
  const int base = blockIdx.x * 256;
  const int e = base + t;
  const bool full = (base + 256 <= E);
  if (full) {
    const float4* src = (const float4*)(y + (size_t)base * 64);
#pragma unroll
    for (int it = 0; it < 16; it++) {
      const int f4 = t + it * 256;
      const int el = f4 >> 4;
      const int cb = (f4 & 15) << 2;
      float4 r = src[f4];
      sbuf[lds_idx(cb + 0, el)] = r.x;
      sbuf[lds_idx(cb + 1, el)] = r.y;
      sbuf[lds_idx(cb + 2, el)] = r.z;
      sbuf[lds_idx(cb + 3, el)] = r.w;
    }
    __syncthreads();
  }
  if (e < E) {
    const double m = statIn[0] * inv_n;
    const double v = statIn[1] * inv_n - m * m;
    const float fm = (float)m;
    const float finv = (float)(1.0 / sqrt(v + LN_EPS));
    float tv[64];
    if (full) {
#pragma unroll
      for (int c = 0; c < 64; c++) {
        const float val = (sbuf[lds_idx(c, t)] - fm) * finv;
        const float tvv = val > 0.f ? val : 0.f;
        tv[c] = tvv;
        sbuf[lds_idx(c, t)] = tvv;  // own column: safe overwrite
      }
    } else {
#pragma unroll
      for (int c = 0; c < 64; c++) {
        const float val = (y[(size_t)e * 64 + c] - fm) * finv;
        const float tvv = val > 0.f ? val : 0.f;
        tv[c] = tvv;
        y[(size_t)e * 64 + c] = tvv;
      }
    }
#pragma unroll
    for (int c = 0; c < 64; c++) {
      float acc = 0.f;
#pragma unroll
      for (int k = 0; k < 64; k++) acc += W[c * 64 + k] * tv[k];
      xe[(size_t)c * E + e] += H_COEF * acc;
    }
  }
  if (full) {
    __syncthreads();
    float4* dst = (float4*)(y + (size_t)base * 64);
#pragma unroll
    for (int it = 0; it < 16; it++) {
      const int f4 = t + it * 256;
      const int el = f4 >> 4;
      const int cb = (f4 & 15) << 2;
      float4 r;
      r.x = sbuf[lds_idx(cb + 0, el)];
      r.y = sbuf[lds_idx(cb + 1, el)];
      r.z = sbuf[lds_idx(cb + 2, el)];
      r.w = sbuf[lds_idx(cb + 3, el)];
      dst[f4] = r;
    }
  }
}

// ---------------------------------------------------------------------------
// gather: Si[n][c] = sum over edges e with i(e)=n of y[e][c]  (y holds t2);
//         Sj likewise for j.  One 64-lane wave per node.
// ---------------------------------------------------------------------------
__global__ __launch_bounds__(256) void gather_kernel(
    const float* __restrict__ y, const int* __restrict__ rowptr_i,
    const int* __restrict__ perm_i, const int* __restrict__ rowptr_j,
    const int* __restrict__ perm_j, float* __restrict__ Si,
    float* __restrict__ Sj, int N) {
  const int n = blockIdx.x * (blockDim.x >> 6) + (threadIdx.x >> 6);
  const int c = threadIdx.x & 63;
  if (n >= N) return;

  float acc = 0.f;
  for (int p = rowptr_i[n]; p < rowptr_i[n + 1]; ++p)
    acc += y[(size_t)perm_i[p] * 64 + c];
  Si[(size_t)n * 64 + c] = acc;

  acc = 0.f;
  for (int p = rowptr_j[n]; p < rowptr_j[n + 1]; ++p)
    acc += y[(size_t)perm_j[p] * 64 + c];
  Sj[(size_t)n * 64 + c] = acc;
}

// ---------------------------------------------------------------------------
// node update, split in two to stay within 256 VGPRs.
// ---------------------------------------------------------------------------
__global__ __launch_bounds__(256) void node_a_kernel(
    const float* __restrict__ KN_l, const float* __restrict__ Si,
    const float* __restrict__ Sj, float* __restrict__ tmp, int N) {
  const int n = blockIdx.x * blockDim.x + threadIdx.x;
  if (n >= N) return;
  float a[64], d[64];
#pragma unroll
  for (int k = 0; k < 64; k++) {
    const float si = Si[(size_t)n * 64 + k];
    const float sj = Sj[(size_t)n * 64 + k];
    a[k] = 0.5f * (si + sj);
    d[k] = si - sj;
  }
#pragma unroll
  for (int c = 0; c < 64; c++) {
    const float* row = KN_l + c * 192;
    float acc = 0.f;
#pragma unroll
    for (int k = 0; k < 64; k++) {
      acc += row[k] * a[k];
      acc += row[128 + k] * d[k];
    }
    tmp[(size_t)c * N + n] = acc;
  }
}

__global__ __launch_bounds__(256) void node_b_kernel(
    const float* __restrict__ KN_l, float* xn, const float* __restrict__ tmp,
    int N) {
  const int n = blockIdx.x * blockDim.x + threadIdx.x;
  if (n >= N) return;
  float x[64];
#pragma unroll
  for (int k = 0; k < 64; k++) x[k] = xn[(size_t)k * N + n];
#pragma unroll
  for (int c = 0; c < 64; c++) {
    const float* row = KN_l + c * 192 + 64;
    float acc = tmp[(size_t)c * N + n];
#pragma unroll
    for (int k = 0; k < 64; k++) acc += row[k] * x[k];
    xn[(size_t)c * N + n] = x[c] + H_COEF * acc;
  }
}

// ---------------------------------------------------------------------------
extern "C" void kernel_launch(void* const* d_in, const int* in_sizes, int n_in,
                              void* d_out, int out_size, void* d_ws,
                              size_t ws_size, hipStream_t stream) {
  const float* xn_in = (const float*)d_in[0];
  const float* xe_in = (const float*)d_in[1];
  const int* iInd = (const int*)d_in[2];
  const int* jInd = (const int*)d_in[3];
  const float* KNopen = (const float*)d_in[4];
  const float* KEopen = (const float*)d_in[5];
  const float* KNclose = (const float*)d_in[6];
  const float* KEclose = (const float*)d_in[7];
  const float* KE1 = (const float*)d_in[8];
  const float* KE2 = (const float*)d_in[9];
  const float* KE3 = (const float*)d_in[10];
  const float* KN = (const float*)d_in[11];

  const int N = in_sizes[0] / 16;               // 20000
  const int E = in_sizes[2];                    // 320000
  const int nlayer = in_sizes[8] / (64 * 192);  // 4

  float* out = (float*)d_out;
  float* xn = out;                   // 64*N
  float* xe = out + (size_t)64 * N;  // 64*E

  float* ws = (float*)d_ws;
  float* y = ws;                  // 64*E   ([E][64] layout)
  float* U = y + (size_t)64 * E;  // [N][64]
  float* V = U + (size_t)64 * N;
  float* Si = V + (size_t)64 * N;
  float* Sj = Si + (size_t)64 * N;
  float* tmp = Sj + (size_t)64 * N;  // [64][N]
  double* stat = (double*)(tmp + (size_t)64 * N);  // nlayer*4 doubles
  int* cnt_i = (int*)(stat + 4 * nlayer);
  int* cnt_j = cnt_i + N;
  int* rowptr_i = cnt_j + N;
  int* cursor_i = rowptr_i + (N + 1);
  int* rowptr_j = cursor_i + N;
  int* cursor_j = rowptr_j + (N + 1);
  int* perm_i = cursor_j + N;
  int* perm_j = perm_i + E;

  const int bn = (N + 255) / 256;
  const int be = (E + 255) / 256;
  const int bg = (N + 3) / 4;
  const double inv_n = 1.0 / (64.0 * (double)E);

  hipMemsetAsync(stat, 0, (size_t)nlayer * 4 * sizeof(double), stream);
  hipMemsetAsync(cnt_i, 0, (size_t)2 * N * sizeof(int), stream);

  hist_kernel<<<be, 256, 0, stream>>>(iInd, jInd, cnt_i, cnt_j, E);
  scan_kernel<<<1, 1024, 0, stream>>>(cnt_i, cnt_j, rowptr_i, cursor_i,
                                      rowptr_j, cursor_j, N);
  fill_kernel<<<be, 256, 0, stream>>>(iInd, jInd, cursor_i, cursor_j, perm_i,
                                      perm_j, E);

  open_kernel<16><<<bn, 256, 0, stream>>>(KNopen, xn_in, xn, N);
  open_kernel<16><<<be, 256, 0, stream>>>(KEopen, xe_in, xe, E);

  for (int l = 0; l < nlayer; l++) {
    const float* KE1_l = KE1 + (size_t)l * 64 * 192;
    const float* KE2_l = KE2 + (size_t)l * 64 * 64;
    const float* KE3_l = KE3 + (size_t)l * 64 * 64;
    const float* KN_l = KN + (size_t)l * 64 * 192;
    double* st1 = stat + (size_t)l * 4;
    double* st2 = st1 + 2;

    uv_kernel<<<bn, 256, 0, stream>>>(KE1_l, xn, U, V, N);
    edge1_kernel<<<be, 256, 0, stream>>>(KE1_l, xe, U, V, iInd, jInd, y, st1,
                                         E);
    edge2_kernel<<<be, 256, 0, stream>>>(KE2_l, y, st1, st2, inv_n, E);
    edge3_kernel<<<be, 256, 0, stream>>>(KE3_l, y, xe, st2, inv_n, E);
    gather_kernel<<<bg, 256, 0, stream>>>(y, rowptr_i, perm_i, rowptr_j,
                                          perm_j, Si, Sj, N);
    node_a_kernel<<<bn, 256, 0, stream>>>(KN_l, Si, Sj, tmp, N);
    node_b_kernel<<<bn, 256, 0, stream>>>(KN_l, xn, tmp, N);
  }

  close_inplace_kernel<<<bn, 256, 0, stream>>>(KNclose, xn, N);
  close_inplace_kernel<<<be, 256, 0, stream>>>(KEclose, xe, E);
}

// Round 5
// 2163.204 us; speedup vs baseline: 1.7641x; 1.7641x over previous
//
#include <hip/hip_runtime.h>
#include <math.h>

#define H_COEF 0.1f
#define LN_EPS 1e-5

// LDS tile swizzle for edge kernels: idx(c, el) = c*256 + (el ^ c).
__device__ __forceinline__ int lds_idx(int c, int el) {
  return (c << 8) + (el ^ c);
}

// ---------------------------------------------------------------------------
// Block-level (sum, sumsq) reduction -> atomicAdd(double) to global stat[2].
// ---------------------------------------------------------------------------
__device__ __forceinline__ void stat_reduce(float s, float ss, double* stat) {
#pragma unroll
  for (int off = 32; off > 0; off >>= 1) {
    s += __shfl_down(s, off);
    ss += __shfl_down(ss, off);
  }
  __shared__ float bs[8], bss[8];
  const int wid = threadIdx.x >> 6;
  const int lane = threadIdx.x & 63;
  if (lane == 0) { bs[wid] = s; bss[wid] = ss; }
  __syncthreads();
  if (threadIdx.x == 0) {
    float S = 0.f, SS = 0.f;
    const int nw = blockDim.x >> 6;
    for (int w = 0; w < nw; w++) { S += bs[w]; SS += bss[w]; }
    atomicAdd(stat, (double)S);
    atomicAdd(stat + 1, (double)SS);
  }
}

// ---------------------------------------------------------------------------
// Weight prep: transposed (and pre-combined) copies, [k][c] layout.
//   WUT[l][k][c] = 0.5*KE1[l][c][k] + KE1[l][c][128+k]
//   WVT[l][k][c] = 0.5*KE1[l][c][k] - KE1[l][c][128+k]
//   WNaT/WNbT/WNcT[l][k][c] = KN[l][c][k] / KN[l][c][64+k] / KN[l][c][128+k]
//   WNopT[k][c] = KNopen[c][k] (k<16);  WNclT[k][c] = KNclose[c][k]
// ---------------------------------------------------------------------------
__global__ __launch_bounds__(256) void prep_weights_kernel(
    const float* __restrict__ KE1, const float* __restrict__ KN,
    const float* __restrict__ KNopen, const float* __restrict__ KNclose,
    float* __restrict__ WUT, float* __restrict__ WVT, float* __restrict__ WNaT,
    float* __restrict__ WNbT, float* __restrict__ WNcT,
    float* __restrict__ WNopT, float* __restrict__ WNclT, int nlayer) {
  const int idx = blockIdx.x * blockDim.x + threadIdx.x;
  const int total = nlayer * 4096;
  if (idx < total) {
    const int l = idx >> 12;
    const int r = idx & 4095;
    const int k = r >> 6;
    const int c = r & 63;
    const float a = KE1[(size_t)l * 12288 + c * 192 + k];
    const float g = KE1[(size_t)l * 12288 + c * 192 + 128 + k];
    WUT[idx] = 0.5f * a + g;
    WVT[idx] = 0.5f * a - g;
    WNaT[idx] = KN[(size_t)l * 12288 + c * 192 + k];
    WNbT[idx] = KN[(size_t)l * 12288 + c * 192 + 64 + k];
    WNcT[idx] = KN[(size_t)l * 12288 + c * 192 + 128 + k];
  }
  if (idx < 4096) {
    const int k = idx >> 6;
    const int c = idx & 63;
    WNclT[idx] = KNclose[c * 64 + k];
    if (k < 16) WNopT[k * 64 + c] = KNopen[c * 16 + k];
  }
}

// ---------------------------------------------------------------------------
// CSR construction (per launch; indices are fixed inputs).
// ---------------------------------------------------------------------------
__global__ __launch_bounds__(256) void hist_kernel(
    const int* __restrict__ iInd, const int* __restrict__ jInd,
    int* __restrict__ cnt_i, int* __restrict__ cnt_j, int E) {
  const int e = blockIdx.x * blockDim.x + threadIdx.x;
  if (e < E) {
    atomicAdd(&cnt_i[iInd[e]], 1);
    atomicAdd(&cnt_j[jInd[e]], 1);
  }
}

__global__ __launch_bounds__(1024) void scan_kernel(
    const int* __restrict__ cnt_i, const int* __restrict__ cnt_j,
    int* __restrict__ rowptr_i, int* __restrict__ cursor_i,
    int* __restrict__ rowptr_j, int* __restrict__ cursor_j, int N) {
  __shared__ int carry;
  __shared__ int tmp[1024];
  for (int pass = 0; pass < 2; ++pass) {
    const int* cnt = pass ? cnt_j : cnt_i;
    int* rp = pass ? rowptr_j : rowptr_i;
    int* cur = pass ? cursor_j : cursor_i;
    if (threadIdx.x == 0) carry = 0;
    __syncthreads();
    for (int base = 0; base < N; base += 1024) {
      const int idx = base + threadIdx.x;
      const int v = (idx < N) ? cnt[idx] : 0;
      tmp[threadIdx.x] = v;
      int acc = v;
      __syncthreads();
      for (int off = 1; off < 1024; off <<= 1) {
        const int add = (threadIdx.x >= off) ? tmp[threadIdx.x - off] : 0;
        __syncthreads();
        acc += add;
        tmp[threadIdx.x] = acc;
        __syncthreads();
      }
      const int excl = acc - v + carry;
      if (idx < N) { rp[idx] = excl; cur[idx] = excl; }
      __syncthreads();
      if (threadIdx.x == 1023) carry += tmp[1023];
      __syncthreads();
    }
    if (threadIdx.x == 0) rp[N] = carry;
    __syncthreads();
  }
}

__global__ __launch_bounds__(256) void fill_kernel(
    const int* __restrict__ iInd, const int* __restrict__ jInd,
    int* __restrict__ cursor_i, int* __restrict__ cursor_j,
    int* __restrict__ perm_i, int* __restrict__ perm_j, int E) {
  const int e = blockIdx.x * blockDim.x + threadIdx.x;
  if (e < E) {
    perm_i[atomicAdd(&cursor_i[iInd[e]], 1)] = e;
    perm_j[atomicAdd(&cursor_j[jInd[e]], 1)] = e;
  }
}

// ---------------------------------------------------------------------------
// Edge-side open / close (feature-major xe, one thread per edge).
// ---------------------------------------------------------------------------
template <int KIN>
__global__ __launch_bounds__(256) void open_kernel(
    const float* __restrict__ W, const float* __restrict__ xin,
    float* __restrict__ out, int M) {
  const int e = blockIdx.x * blockDim.x + threadIdx.x;
  if (e >= M) return;
  float x[KIN];
#pragma unroll
  for (int k = 0; k < KIN; k++) x[k] = xin[(size_t)k * M + e];
#pragma unroll
  for (int c = 0; c < 64; c++) {
    float acc = 0.f;
#pragma unroll
    for (int k = 0; k < KIN; k++) acc += W[c * KIN + k] * x[k];
    out[(size_t)c * M + e] = acc;
  }
}

__global__ __launch_bounds__(256) void close_inplace_kernel(
    const float* __restrict__ W, float* x, int M) {
  const int e = blockIdx.x * blockDim.x + threadIdx.x;
  if (e >= M) return;
  float xv[64];
#pragma unroll
  for (int k = 0; k < 64; k++) xv[k] = x[(size_t)k * M + e];
#pragma unroll
  for (int c = 0; c < 64; c++) {
    float acc = 0.f;
#pragma unroll
    for (int k = 0; k < 64; k++) acc += W[c * 64 + k] * xv[k];
    x[(size_t)c * M + e] = acc;
  }
}

// ---------------------------------------------------------------------------
// Node-side open: xn_node[n][c] = sum_k WNopT[k][c] * xn_in[k][n].
// One wave per node; lane = output channel c.
// ---------------------------------------------------------------------------
__global__ __launch_bounds__(256) void open_node_kernel(
    const float* __restrict__ WNopT, const float* __restrict__ xn_in,
    float* __restrict__ xn_node, int N) {
  const int n = blockIdx.x * 4 + (threadIdx.x >> 6);
  const int c = threadIdx.x & 63;
  if (n >= N) return;
  const float xv = (c < 16) ? xn_in[(size_t)c * N + n] : 0.f;
  float acc = 0.f;
#pragma unroll
  for (int k = 0; k < 16; k++) {
    const float xk = __shfl(xv, k);
    acc += WNopT[k * 64 + c] * xk;
  }
  xn_node[(size_t)n * 64 + c] = acc;
}

// ---------------------------------------------------------------------------
// Node-side close: out[c][n] = sum_k WNclT[k][c] * xn_node[n][k].
// ---------------------------------------------------------------------------
__global__ __launch_bounds__(256) void close_node_kernel(
    const float* __restrict__ WNclT, const float* __restrict__ xn_node,
    float* __restrict__ out, int N) {
  const int n = blockIdx.x * 4 + (threadIdx.x >> 6);
  const int c = threadIdx.x & 63;
  if (n >= N) return;
  const float xv = xn_node[(size_t)n * 64 + c];
  float acc = 0.f;
#pragma unroll
  for (int k = 0; k < 64; k++) {
    const float xk = __shfl(xv, k);
    acc += WNclT[k * 64 + c] * xk;
  }
  out[(size_t)c * N + n] = acc;
}

// ---------------------------------------------------------------------------
// uv: U[n][c] = sum_k WUT[k][c]*xn_node[n][k];  V likewise with WVT.
// One wave per node; all global accesses coalesced rows.
// ---------------------------------------------------------------------------
__global__ __launch_bounds__(256) void uv_kernel(
    const float* __restrict__ WUT, const float* __restrict__ WVT,
    const float* __restrict__ xn_node, float* __restrict__ U,
    float* __restrict__ V, int N) {
  const int n = blockIdx.x * 4 + (threadIdx.x >> 6);
  const int c = threadIdx.x & 63;
  if (n >= N) return;
  const float xv = xn_node[(size_t)n * 64 + c];
  float ua = 0.f, va = 0.f;
#pragma unroll
  for (int k = 0; k < 64; k++) {
    const float xk = __shfl(xv, k);
    ua += WUT[k * 64 + c] * xk;
    va += WVT[k * 64 + c] * xk;
  }
  U[(size_t)n * 64 + c] = ua;
  V[(size_t)n * 64 + c] = va;
}

// ---------------------------------------------------------------------------
// edge1: y[e][:] = U[i(e)][:] + V[j(e)][:] + B1 @ xe[:,e];  stats of y.
// y row-major [E][64]; stores staged via LDS (full-line global writes).
// ---------------------------------------------------------------------------
__global__ __launch_bounds__(256) void edge1_kernel(
    const float* __restrict__ KE1_l, const float* __restrict__ xe,
    const float* __restrict__ U, const float* __restrict__ V,
    const int* __restrict__ iInd, const int* __restrict__ jInd,
    float* __restrict__ y, double* __restrict__ stat, int E) {
  __shared__ float sbuf[16384];
  const int t = threadIdx.x;
  const int base = blockIdx.x * 256;
  const int e = base + t;
  const bool full = (base + 256 <= E);
  float s = 0.f, ss = 0.f;
  if (e < E) {
    const int vi = iInd[e];
    const int vj = jInd[e];
    const float4* Up = (const float4*)(U + (size_t)vi * 64);
    const float4* Vp = (const float4*)(V + (size_t)vj * 64);
    float x[64];
#pragma unroll
    for (int k = 0; k < 64; k++) x[k] = xe[(size_t)k * E + e];
#pragma unroll
    for (int q = 0; q < 16; q++) {
      float4 uq = Up[q];
      float4 vq = Vp[q];
      const float* up = (const float*)&uq;
      const float* vp = (const float*)&vq;
#pragma unroll
      for (int u = 0; u < 4; u++) {
        const int c = q * 4 + u;
        const float* row = KE1_l + c * 192 + 64;
        float acc = up[u] + vp[u];
#pragma unroll
        for (int k = 0; k < 64; k++) acc += row[k] * x[k];
        s += acc;
        ss += acc * acc;
        if (full) sbuf[lds_idx(c, t)] = acc;
        else y[(size_t)e * 64 + c] = acc;
      }
    }
  }
  if (full) {
    __syncthreads();
    float4* dst = (float4*)(y + (size_t)base * 64);
#pragma unroll
    for (int it = 0; it < 16; it++) {
      const int f4 = t + it * 256;
      const int el = f4 >> 4;
      const int cb = (f4 & 15) << 2;
      float4 r;
      r.x = sbuf[lds_idx(cb + 0, el)];
      r.y = sbuf[lds_idx(cb + 1, el)];
      r.z = sbuf[lds_idx(cb + 2, el)];
      r.w = sbuf[lds_idx(cb + 3, el)];
      dst[f4] = r;
    }
  }
  stat_reduce(s, ss, stat);
}

// ---------------------------------------------------------------------------
// edge2: t = relu(ln(y row)); y row <- KE2 @ t (in place); stats of new y.
// ---------------------------------------------------------------------------
__global__ __launch_bounds__(256) void edge2_kernel(
    const float* __restrict__ W, float* y, const double* __restrict__ statIn,
    double* __restrict__ statOut, double inv_n, int E) {
  __shared__ float sbuf[16384];
  const int t = threadIdx.x;
  const int base = blockIdx.x * 256;
  const int e = base + t;
  const bool full = (base + 256 <= E);
  float s = 0.f, ss = 0.f;
  if (full) {
    const float4* src = (const float4*)(y + (size_t)base * 64);
#pragma unroll
    for (int it = 0; it < 16; it++) {
      const int f4 = t + it * 256;
      const int el = f4 >> 4;
      const int cb = (f4 & 15) << 2;
      float4 r = src[f4];
      sbuf[lds_idx(cb + 0, el)] = r.x;
      sbuf[lds_idx(cb + 1, el)] = r.y;
      sbuf[lds_idx(cb + 2, el)] = r.z;
      sbuf[lds_idx(cb + 3, el)] = r.w;
    }
    __syncthreads();
  }
  if (e < E) {
    const double m = statIn[0] * inv_n;
    const double v = statIn[1] * inv_n - m * m;
    const float fm = (float)m;
    const float finv = (float)(1.0 / sqrt(v + LN_EPS));
    float tv[64];
    if (full) {
#pragma unroll
      for (int c = 0; c < 64; c++) {
        const float val = (sbuf[lds_idx(c, t)] - fm) * finv;
        tv[c] = val > 0.f ? val : 0.f;
      }
    } else {
#pragma unroll
      for (int c = 0; c < 64; c++) {
        const float val = (y[(size_t)e * 64 + c] - fm) * finv;
        tv[c] = val > 0.f ? val : 0.f;
      }
    }
#pragma unroll
    for (int c = 0; c < 64; c++) {
      float acc = 0.f;
#pragma unroll
      for (int k = 0; k < 64; k++) acc += W[c * 64 + k] * tv[k];
      s += acc;
      ss += acc * acc;
      if (full) sbuf[lds_idx(c, t)] = acc;
      else y[(size_t)e * 64 + c] = acc;
    }
  }
  if (full) {
    __syncthreads();
    float4* dst = (float4*)(y + (size_t)base * 64);
#pragma unroll
    for (int it = 0; it < 16; it++) {
      const int f4 = t + it * 256;
      const int el = f4 >> 4;
      const int cb = (f4 & 15) << 2;
      float4 r;
      r.x = sbuf[lds_idx(cb + 0, el)];
      r.y = sbuf[lds_idx(cb + 1, el)];
      r.z = sbuf[lds_idx(cb + 2, el)];
      r.w = sbuf[lds_idx(cb + 3, el)];
      dst[f4] = r;
    }
  }
  stat_reduce(s, ss, statOut);
}

// ---------------------------------------------------------------------------
// edge3: t2 = relu(ln(y row));  xe col += H * (KE3 @ t2).  y unchanged.
// ---------------------------------------------------------------------------
__global__ __launch_bounds__(256) void edge3_kernel(
    const float* __restrict__ W, const float* __restrict__ y, float* xe,
    const double* __restrict__ statIn, double inv_n, int E) {
  const int e = blockIdx.x * blockDim.x + threadIdx.x;
  if (e >= E) return;
  const double m = statIn[0] * inv_n;
  const double v = statIn[1] * inv_n - m * m;
  const float fm = (float)m;
  const float finv = (float)(1.0 / sqrt(v + LN_EPS));
  float tv[64];
  const float4* yrow = (const float4*)(y + (size_t)e * 64);
#pragma unroll
  for (int q = 0; q < 16; q++) {
    float4 r = yrow[q];
    const float* rp = (const float*)&r;
#pragma unroll
    for (int u = 0; u < 4; u++) {
      const float val = (rp[u] - fm) * finv;
      tv[q * 4 + u] = val > 0.f ? val : 0.f;
    }
  }
#pragma unroll
  for (int c = 0; c < 64; c++) {
    float acc = 0.f;
#pragma unroll
    for (int k = 0; k < 64; k++) acc += W[c * 64 + k] * tv[k];
    xe[(size_t)c * E + e] += H_COEF * acc;
  }
}

// ---------------------------------------------------------------------------
// fused node update: one wave per node; lane = channel c.
//   si = sum_{e in i-list} relu(ln(y[e][c]));  sj likewise (j-list)
//   a = 0.5*(si+sj); d = si-sj; xv = xn_node[n][c]
//   acc_c = sum_k ( WNaT[k][c]*a_k + WNbT[k][c]*xv_k + WNcT[k][c]*d_k )
//   xn_node[n][c] = xv + H*acc_c
// ---------------------------------------------------------------------------
__global__ __launch_bounds__(256) void fused_node_kernel(
    const float* __restrict__ y, const int* __restrict__ rowptr_i,
    const int* __restrict__ perm_i, const int* __restrict__ rowptr_j,
    const int* __restrict__ perm_j, const float* __restrict__ WNaT,
    const float* __restrict__ WNbT, const float* __restrict__ WNcT,
    float* __restrict__ xn_node, const double* __restrict__ statIn,
    double inv_n, int N) {
  const int n = blockIdx.x * 4 + (threadIdx.x >> 6);
  const int c = threadIdx.x & 63;
  if (n >= N) return;
  const double m = statIn[0] * inv_n;
  const double v = statIn[1] * inv_n - m * m;
  const float fm = (float)m;
  const float finv = (float)(1.0 / sqrt(v + LN_EPS));

  float si = 0.f;
  const int ib = rowptr_i[n], ie = rowptr_i[n + 1];
  for (int p = ib; p < ie; ++p) {
    const float val = (y[(size_t)perm_i[p] * 64 + c] - fm) * finv;
    si += val > 0.f ? val : 0.f;
  }
  float sj = 0.f;
  const int jb = rowptr_j[n], je = rowptr_j[n + 1];
  for (int p = jb; p < je; ++p) {
    const float val = (y[(size_t)perm_j[p] * 64 + c] - fm) * finv;
    sj += val > 0.f ? val : 0.f;
  }

  const float xv = xn_node[(size_t)n * 64 + c];
  const float a = 0.5f * (si + sj);
  const float d = si - sj;
  float acc = 0.f;
#pragma unroll
  for (int k = 0; k < 64; k++) {
    const float ak = __shfl(a, k);
    const float xk = __shfl(xv, k);
    const float dk = __shfl(d, k);
    acc += WNaT[k * 64 + c] * ak;
    acc += WNbT[k * 64 + c] * xk;
    acc += WNcT[k * 64 + c] * dk;
  }
  xn_node[(size_t)n * 64 + c] = xv + H_COEF * acc;
}

// ---------------------------------------------------------------------------
extern "C" void kernel_launch(void* const* d_in, const int* in_sizes, int n_in,
                              void* d_out, int out_size, void* d_ws,
                              size_t ws_size, hipStream_t stream) {
  const float* xn_in = (const float*)d_in[0];
  const float* xe_in = (const float*)d_in[1];
  const int* iInd = (const int*)d_in[2];
  const int* jInd = (const int*)d_in[3];
  const float* KNopen = (const float*)d_in[4];
  const float* KEopen = (const float*)d_in[5];
  const float* KNclose = (const float*)d_in[6];
  const float* KEclose = (const float*)d_in[7];
  const float* KE1 = (const float*)d_in[8];
  const float* KE2 = (const float*)d_in[9];
  const float* KE3 = (const float*)d_in[10];
  const float* KN = (const float*)d_in[11];

  const int N = in_sizes[0] / 16;               // 20000
  const int E = in_sizes[2];                    // 320000
  const int nlayer = in_sizes[8] / (64 * 192);  // 4

  float* out = (float*)d_out;
  float* xn_out = out;               // [64][N] feature-major (final)
  float* xe = out + (size_t)64 * N;  // [64][E] feature-major, in-place

  float* ws = (float*)d_ws;
  float* y = ws;                          // [E][64]
  float* U = y + (size_t)64 * E;          // [N][64]
  float* V = U + (size_t)64 * N;          // [N][64]
  float* xn_node = V + (size_t)64 * N;    // [N][64]
  float* WUT = xn_node + (size_t)64 * N;  // nlayer*4096 each
  float* WVT = WUT + (size_t)4096 * nlayer;
  float* WNaT = WVT + (size_t)4096 * nlayer;
  float* WNbT = WNaT + (size_t)4096 * nlayer;
  float* WNcT = WNbT + (size_t)4096 * nlayer;
  float* WNopT = WNcT + (size_t)4096 * nlayer;  // 1024
  float* WNclT = WNopT + 1024;                  // 4096
  double* stat = (double*)(WNclT + 4096);       // nlayer*4 doubles
  int* cnt_i = (int*)(stat + 4 * nlayer);
  int* cnt_j = cnt_i + N;
  int* rowptr_i = cnt_j + N;
  int* cursor_i = rowptr_i + (N + 1);
  int* rowptr_j = cursor_i + N;
  int* cursor_j = rowptr_j + (N + 1);
  int* perm_i = cursor_j + N;
  int* perm_j = perm_i + E;

  const int be = (E + 255) / 256;
  const int bw = (N + 3) / 4;  // wave-per-node kernels
  const double inv_n = 1.0 / (64.0 * (double)E);

  hipMemsetAsync(stat, 0, (size_t)nlayer * 4 * sizeof(double), stream);
  hipMemsetAsync(cnt_i, 0, (size_t)2 * N * sizeof(int), stream);

  prep_weights_kernel<<<(nlayer * 4096 + 255) / 256, 256, 0, stream>>>(
      KE1, KN, KNopen, KNclose, WUT, WVT, WNaT, WNbT, WNcT, WNopT, WNclT,
      nlayer);

  hist_kernel<<<be, 256, 0, stream>>>(iInd, jInd, cnt_i, cnt_j, E);
  scan_kernel<<<1, 1024, 0, stream>>>(cnt_i, cnt_j, rowptr_i, cursor_i,
                                      rowptr_j, cursor_j, N);
  fill_kernel<<<be, 256, 0, stream>>>(iInd, jInd, cursor_i, cursor_j, perm_i,
                                      perm_j, E);

  open_node_kernel<<<bw, 256, 0, stream>>>(WNopT, xn_in, xn_node, N);
  open_kernel<16><<<be, 256, 0, stream>>>(KEopen, xe_in, xe, E);

  for (int l = 0; l < nlayer; l++) {
    const float* KE1_l = KE1 + (size_t)l * 64 * 192;
    const float* KE2_l = KE2 + (size_t)l * 64 * 64;
    const float* KE3_l = KE3 + (size_t)l * 64 * 64;
    double* st1 = stat + (size_t)l * 4;
    double* st2 = st1 + 2;

    uv_kernel<<<bw, 256, 0, stream>>>(WUT + (size_t)l * 4096,
                                      WVT + (size_t)l * 4096, xn_node, U, V, N);
    edge1_kernel<<<be, 256, 0, stream>>>(KE1_l, xe, U, V, iInd, jInd, y, st1,
                                         E);
    edge2_kernel<<<be, 256, 0, stream>>>(KE2_l, y, st1, st2, inv_n, E);
    edge3_kernel<<<be, 256, 0, stream>>>(KE3_l, y, xe, st2, inv_n, E);
    fused_node_kernel<<<bw, 256, 0, stream>>>(
        y, rowptr_i, perm_i, rowptr_j, perm_j, WNaT + (size_t)l * 4096,
        WNbT + (size_t)l * 4096, WNcT + (size_t)l * 4096, xn_node, st2, inv_n,
        N);
  }

  close_node_kernel<<<bw, 256, 0, stream>>>(WNclT, xn_node, xn_out, N);
  close_inplace_kernel<<<be, 256, 0, stream>>>(KEclose, xe, E);
}